// Round 8
// baseline (313.438 us; speedup 1.0000x reference)
//
#include <hip/hip_runtime.h>
#include <cstddef>
#include <cstdint>

// Problem constants (B=2, S=2048, D=1024, H=16, hd=64)
constexpr int Bb = 2, Ss = 2048, Dd = 1024, Hh = 16, HD = 64;
constexpr int Mm = Bb * Ss;  // 4096 rows

typedef int v4i __attribute__((ext_vector_type(4)));
typedef __bf16 bf16x8 __attribute__((ext_vector_type(8)));
typedef __bf16 bf16x2 __attribute__((ext_vector_type(2)));
typedef float f32x16 __attribute__((ext_vector_type(16)));

// ln2 folding: q *= 0.125 * 1/ln2 so p = exp2(score) is one v_exp_f32
#define QPOSTMUL 0.18033688f
#define MASKBIAS -14426.950408f   /* -10000 / ln2 */

__device__ __forceinline__ float qscale(float amax) {
    return fmaxf(amax / 127.0f, 1e-8f);
}

// round-to-nearest-even f32 -> bf16 bits
__device__ __forceinline__ unsigned short bf16rtn(float x) {
    __bf16 b = (__bf16)x;
    return __builtin_bit_cast(unsigned short, b);
}

// pack two f32 -> bf16x2 in one u32 (RTN; compiler emits v_cvt_pk_bf16_f32)
__device__ __forceinline__ unsigned pack_bf16x2(float a, float b) {
    bf16x2 v;
    v[0] = (__bf16)a;
    v[1] = (__bf16)b;
    return __builtin_bit_cast(unsigned, v);
}

// ---------------- fused amax: hidden (slot0) + 4 weights (slots 1-4) ----------------
__global__ void amax_all(const float4* __restrict__ hidden,
                         const float4* __restrict__ w0, const float4* __restrict__ w1,
                         const float4* __restrict__ w2, const float4* __restrict__ w3,
                         unsigned* __restrict__ slots) {
    const float4* src; int n4, slot, bx, nb;
    if (blockIdx.x < 448) { src = hidden; n4 = Mm * Dd / 4; slot = 0; bx = blockIdx.x; nb = 448; }
    else {
        int w = (blockIdx.x - 448) >> 4; bx = (blockIdx.x - 448) & 15; nb = 16;
        src = w == 0 ? w0 : w == 1 ? w1 : w == 2 ? w2 : w3;
        n4 = Dd * Dd / 4; slot = 1 + w;
    }
    float m = 0.f;
    for (int i = bx * blockDim.x + threadIdx.x; i < n4; i += nb * blockDim.x) {
        float4 v = src[i];
        m = fmaxf(m, fmaxf(fmaxf(fabsf(v.x), fabsf(v.y)), fmaxf(fabsf(v.z), fabsf(v.w))));
    }
    #pragma unroll
    for (int off = 32; off > 0; off >>= 1) m = fmaxf(m, __shfl_down(m, off, 64));
    __shared__ float sm[4];
    int lane = threadIdx.x & 63, wid = threadIdx.x >> 6;
    if (lane == 0) sm[wid] = m;
    __syncthreads();
    if (threadIdx.x == 0) {
        float mm = fmaxf(fmaxf(sm[0], sm[1]), fmaxf(sm[2], sm[3]));
        atomicMax(slots + slot, __float_as_uint(mm));  // f32 bits compare as uint for >=0
    }
}

// ---------------- fused quant: hidden -> hq8, 4 weights -> Wall8 (1MB apart) ------------
__global__ void quant_all(const float* __restrict__ hidden,
                          const float* __restrict__ w0, const float* __restrict__ w1,
                          const float* __restrict__ w2, const float* __restrict__ w3,
                          const float* __restrict__ amax,
                          char* __restrict__ hq8, char* __restrict__ Wall8) {
    const float* x; char* y; int n4, slot, bx, nb;
    if (blockIdx.x < 1024) { x = hidden; y = hq8; n4 = Mm * Dd / 4; slot = 0; bx = blockIdx.x; nb = 1024; }
    else {
        int w = (blockIdx.x - 1024) >> 5; bx = (blockIdx.x - 1024) & 31; nb = 32;
        x = w == 0 ? w0 : w == 1 ? w1 : w == 2 ? w2 : w3;
        y = Wall8 + ((size_t)w << 20);
        n4 = Dd * Dd / 4; slot = 1 + w;
    }
    float s = qscale(amax[slot]);
    const float4* x4 = (const float4*)x;
    char4* y4 = (char4*)y;
    for (int i = bx * blockDim.x + threadIdx.x; i < n4; i += nb * blockDim.x) {
        float4 v = x4[i];
        char4 q;
        q.x = (char)(int)rintf(v.x / s);
        q.y = (char)(int)rintf(v.y / s);
        q.z = (char)(int)rintf(v.z / s);
        q.w = (char)(int)rintf(v.w / s);
        y4[i] = q;
    }
}

// quant attn output (scale inline from amax slot)
__global__ void quant_a(const float* __restrict__ x, char* __restrict__ y,
                        const float* __restrict__ amax, int n4) {
    float s = qscale(amax[0]);
    int stride = gridDim.x * blockDim.x;
    const float4* x4 = (const float4*)x;
    char4* y4 = (char4*)y;
    for (int i = blockIdx.x * blockDim.x + threadIdx.x; i < n4; i += stride) {
        float4 v = x4[i];
        char4 q;
        q.x = (char)(int)rintf(v.x / s);
        q.y = (char)(int)rintf(v.y / s);
        q.z = (char)(int)rintf(v.z / s);
        q.w = (char)(int)rintf(v.w / s);
        y4[i] = q;
    }
}

// ---------------- int8 MFMA GEMM core: 128x128 tile, BK=64, 4 waves of 64x64 ------------
#define GLOAD_LDS16(g, l) __builtin_amdgcn_global_load_lds( \
    (const __attribute__((address_space(1))) unsigned int*)(g), \
    (__attribute__((address_space(3))) unsigned int*)(l), 16, 0, 0)

__device__ __forceinline__ void gemm128_core(const char* __restrict__ A, const char* __restrict__ Bw,
                                             int bm, int bn, int K, int t,
                                             char* At, char* Bt, v4i acc[4][4]) {
    const int lane = t & 63, w = t >> 6;
    const int wm = (w >> 1) * 64, wn = (w & 1) * 64;
    const int lr = lane & 15, kq = lane >> 4;
    const int rs = w * 16 + (lane >> 2);  // wave-contiguous staged row
    const int cc = lane & 3;

    for (int k0 = 0; k0 < K; k0 += 64) {
        __syncthreads();
        #pragma unroll
        for (int h = 0; h < 2; h++) {
            int r = rs + h * 64;
            int cs = cc ^ ((r >> 1) & 3);  // source-side XOR swizzle
            GLOAD_LDS16(A  + (size_t)(bm + r) * K + k0 + cs * 16, At + r * 64 + cc * 16);
            GLOAD_LDS16(Bw + (size_t)(bn + r) * K + k0 + cs * 16, Bt + r * 64 + cc * 16);
        }
        __syncthreads();

        v4i af[4], bf[4];
        #pragma unroll
        for (int mt = 0; mt < 4; mt++) {
            int row = wm + mt * 16 + lr;
            af[mt] = *(const v4i*)(At + row * 64 + ((kq ^ ((row >> 1) & 3)) << 4));
        }
        #pragma unroll
        for (int nt = 0; nt < 4; nt++) {
            int row = wn + nt * 16 + lr;
            bf[nt] = *(const v4i*)(Bt + row * 64 + ((kq ^ ((row >> 1) & 3)) << 4));
        }
        #pragma unroll
        for (int mt = 0; mt < 4; mt++)
            #pragma unroll
            for (int nt = 0; nt < 4; nt++)
                acc[mt][nt] = __builtin_amdgcn_mfma_i32_16x16x64_i8(af[mt], bf[nt], acc[mt][nt], 0, 0, 0);
    }
}

// Fused Q/K/V projection. Q: bf16 (pre-scaled by 0.125/ln2); K: bf16; V: bf16 transposed.
__global__ __launch_bounds__(256) void gemm_qkv(const char* __restrict__ A,
                                                const char* __restrict__ Wall8,
                                                const float* __restrict__ bq,
                                                const float* __restrict__ bk,
                                                const float* __restrict__ bv,
                                                const float* __restrict__ amax,
                                                unsigned short* __restrict__ qb16,
                                                unsigned short* __restrict__ kb16,
                                                unsigned short* __restrict__ vt16) {
    __shared__ alignas(16) char At[128 * 64];
    __shared__ alignas(16) char Bt[128 * 64];
    const int t = threadIdx.x, lane = t & 63, w = t >> 6;
    const int mat = blockIdx.x >> 3;
    const int bn = (blockIdx.x & 7) * 128, bm = blockIdx.y * 128;
    const int wm = (w >> 1) * 64, wn = (w & 1) * 64;
    const int lr = lane & 15, kq = lane >> 4;

    const v4i vzero = {0, 0, 0, 0};
    v4i acc[4][4];
    #pragma unroll
    for (int mt = 0; mt < 4; mt++)
        #pragma unroll
        for (int nt = 0; nt < 4; nt++) acc[mt][nt] = vzero;

    const char* Bw = Wall8 + ((size_t)mat << 20);
    gemm128_core(A, Bw, bm, bn, Dd, t, At, Bt, acc);

    const float* bias = mat == 0 ? bq : mat == 1 ? bk : bv;
    float sc = qscale(amax[0]) * qscale(amax[1 + mat]);
    float pm = (mat == 0) ? QPOSTMUL : 1.0f;

    #pragma unroll
    for (int nt = 0; nt < 4; nt++) {
        int n = bn + wn + nt * 16 + lr;
        float bv_ = bias[n];
        #pragma unroll
        for (int mt = 0; mt < 4; mt++) {
            if (mat == 2) {  // V^T [B,H,64,S] bf16
                int m0 = bm + wm + mt * 16 + kq * 4;
                int b_ = m0 >> 11, s_ = m0 & 2047;
                int e = n & 63, hc = n >> 6;
                ushort4 hv;
                hv.x = bf16rtn((float)acc[mt][nt][0] * sc + bv_);
                hv.y = bf16rtn((float)acc[mt][nt][1] * sc + bv_);
                hv.z = bf16rtn((float)acc[mt][nt][2] * sc + bv_);
                hv.w = bf16rtn((float)acc[mt][nt][3] * sc + bv_);
                size_t ad = (((size_t)(b_ * Hh + hc) * 64 + e) * Ss) + s_;
                *(ushort4*)(vt16 + ad) = hv;
            } else {
                unsigned short* C = mat == 0 ? qb16 : kb16;
                #pragma unroll
                for (int rg = 0; rg < 4; rg++) {
                    int m = bm + wm + mt * 16 + kq * 4 + rg;
                    C[(size_t)m * Dd + n] = bf16rtn(((float)acc[mt][nt][rg] * sc + bv_) * pm);
                }
            }
        }
    }
}

// O-projection: 128m x 64n tile -> 512 blocks (2/CU) for latency overlap. f32 output.
__global__ __launch_bounds__(256) void gemm_o(const char* __restrict__ A,
                                              const char* __restrict__ Bw,
                                              const float* __restrict__ bias,
                                              const float* __restrict__ amaxA,
                                              const float* __restrict__ amaxB,
                                              float* __restrict__ C) {
    __shared__ alignas(16) char At[128 * 64];
    __shared__ alignas(16) char Bt[64 * 64];
    const int t = threadIdx.x, lane = t & 63, w = t >> 6;
    const int bn = blockIdx.x * 64, bm = blockIdx.y * 128;
    const int wm = (w >> 1) * 64, wn = (w & 1) * 32;
    const int lr = lane & 15, kq = lane >> 4;
    const int rs = t >> 2, cc = t & 3;
    const int cs = cc ^ ((rs >> 1) & 3);
    const int rs2 = rs + 64, cs2 = cc ^ ((rs2 >> 1) & 3);

    const v4i vzero = {0, 0, 0, 0};
    v4i acc[4][2];
    #pragma unroll
    for (int mt = 0; mt < 4; mt++) { acc[mt][0] = vzero; acc[mt][1] = vzero; }

    for (int k0 = 0; k0 < Dd; k0 += 64) {
        __syncthreads();
        GLOAD_LDS16(A  + (size_t)(bm + rs)  * Dd + k0 + cs  * 16, At + rs  * 64 + cc * 16);
        GLOAD_LDS16(A  + (size_t)(bm + rs2) * Dd + k0 + cs2 * 16, At + rs2 * 64 + cc * 16);
        GLOAD_LDS16(Bw + (size_t)(bn + rs)  * Dd + k0 + cs  * 16, Bt + rs  * 64 + cc * 16);
        __syncthreads();

        v4i af[4], bf[2];
        #pragma unroll
        for (int mt = 0; mt < 4; mt++) {
            int row = wm + mt * 16 + lr;
            af[mt] = *(const v4i*)(At + row * 64 + ((kq ^ ((row >> 1) & 3)) << 4));
        }
        #pragma unroll
        for (int nt = 0; nt < 2; nt++) {
            int row = wn + nt * 16 + lr;
            bf[nt] = *(const v4i*)(Bt + row * 64 + ((kq ^ ((row >> 1) & 3)) << 4));
        }
        #pragma unroll
        for (int mt = 0; mt < 4; mt++)
            #pragma unroll
            for (int nt = 0; nt < 2; nt++)
                acc[mt][nt] = __builtin_amdgcn_mfma_i32_16x16x64_i8(af[mt], bf[nt], acc[mt][nt], 0, 0, 0);
    }

    float sc = qscale(amaxA[0]) * qscale(amaxB[0]);
    #pragma unroll
    for (int nt = 0; nt < 2; nt++) {
        int n = bn + wn + nt * 16 + lr;
        float bv_ = bias[n];
        #pragma unroll
        for (int mt = 0; mt < 4; mt++)
            #pragma unroll
            for (int rg = 0; rg < 4; rg++) {
                int m = bm + wm + mt * 16 + kq * 4 + rg;
                C[(size_t)m * Dd + n] = (float)acc[mt][nt][rg] * sc + bv_;
            }
    }
}

// ---------------- MFMA flash attention: barrier-free K-loop -----------------------------
// K/V B-fragments loaded DIRECTLY from global (rows of kb16/vt16 are contiguous k-runs in
// MFMA B layout), double-buffered in registers; L1/L2 serve the 4 waves' shared tiles.
// P is the only LDS traffic (per-wave-private buffer -> wave-internal DS ordering, no
// __syncthreads in the k-loop). tile0/tile1 = even/odd key rows -> P pairs pack to one
// ds_write_b32 via v_cvt_pk_bf16_f32. No-max exp2 softmax (l = pure per-lane sum).
__global__ __launch_bounds__(256) void attn_mfma(
    const unsigned short* __restrict__ qb16, const unsigned short* __restrict__ kb16,
    const unsigned short* __restrict__ vt16,
    const float* __restrict__ mask, float* __restrict__ Ob, unsigned* __restrict__ amax_out) {
    __shared__ alignas(16) unsigned PwU[4][32][36];  // per-wave P, packed (p_even, p_odd)
    __shared__ float wred[4];

    const int t = threadIdx.x, lane = t & 63, wq = t >> 6;
    const int ln31 = lane & 31, h5 = lane >> 5;
    const int b = blockIdx.z, h = blockIdx.y, q0 = blockIdx.x * 128;

    // Q fragments (A operand): row = q0 + wq*32 + ln31, k = c*16 + h5*8 + j
    bf16x8 qf[4];
    {
        int qrow = q0 + wq * 32 + ln31;
        const unsigned short* qb_ = qb16 + ((size_t)(b * Ss + qrow)) * Dd + h * 64 + h5 * 8;
        #pragma unroll
        for (int c = 0; c < 4; c++) qf[c] = *(const bf16x8*)(qb_ + c * 16);
    }

    // global B-frag base pointers
    const unsigned short* kbase = kb16 + ((size_t)(b * Ss)) * Dd + h * 64 + h5 * 8;  // + (k0+key)*Dd + c*16
    const unsigned short* vbase = vt16 + ((size_t)(b * Hh + h) * 64) * Ss + h5 * 8;  // + e*Ss + k0 + c*16
    const float* mbase = mask + b * Ss;

    f32x16 o0 = 0.f, o1 = 0.f;
    float lp[16];
    #pragma unroll
    for (int r = 0; r < 16; r++) lp[r] = 0.f;

    bf16x8 kf[2][8], vf[2][8];
    float mk[2][2];
    // load fragments for tile at k0 into buffer s
    auto loadf = [&](int s, int k0) {
        const unsigned short* ke = kbase + (size_t)(k0 + 2 * ln31) * Dd;      // even key row
        const unsigned short* ko = ke + Dd;                                    // odd key row
        const unsigned short* v0 = vbase + (size_t)ln31 * Ss + k0;             // e = ln31
        const unsigned short* v1 = vbase + (size_t)(32 + ln31) * Ss + k0;      // e = 32+ln31
        #pragma unroll
        for (int c = 0; c < 4; c++) {
            kf[s][c]     = *(const bf16x8*)(ke + c * 16);
            kf[s][4 + c] = *(const bf16x8*)(ko + c * 16);
            vf[s][c]     = *(const bf16x8*)(v0 + c * 16);
            vf[s][4 + c] = *(const bf16x8*)(v1 + c * 16);
        }
        mk[s][0] = mbase[k0 + 2 * ln31];
        mk[s][1] = mbase[k0 + 2 * ln31 + 1];
    };

    auto body = [&](int s, int ns, int k0) {
        if (k0 + 64 < Ss) loadf(ns, k0 + 64);  // prefetch next tile during compute

        // QK^T: tile0 = even key rows, tile1 = odd
        f32x16 sc0 = 0.f, sc1 = 0.f;
        #pragma unroll
        for (int c = 0; c < 4; c++) {
            sc0 = __builtin_amdgcn_mfma_f32_32x32x16_bf16(qf[c], kf[s][c], sc0, 0, 0, 0);
            sc1 = __builtin_amdgcn_mfma_f32_32x32x16_bf16(qf[c], kf[s][4 + c], sc1, 0, 0, 0);
        }

        float mb0 = (1.0f - mk[s][0]) * MASKBIAS;
        float mb1 = (1.0f - mk[s][1]) * MASKBIAS;
        #pragma unroll
        for (int r = 0; r < 16; r++) {
            float p0 = __builtin_amdgcn_exp2f(sc0[r] + mb0);
            float p1 = __builtin_amdgcn_exp2f(sc1[r] + mb1);
            lp[r] += p0 + p1;
            int row = (r & 3) + 8 * (r >> 2) + 4 * h5;
            PwU[wq][row][ln31] = pack_bf16x2(p0, p1);  // keys in natural order as ushorts
        }

        // PV: O += P * V (A-frags from per-wave LDS; compiler inserts lgkmcnt)
        #pragma unroll
        for (int c = 0; c < 4; c++) {
            bf16x8 pf = *(const bf16x8*)((const unsigned short*)&PwU[wq][ln31][0] + c * 16 + h5 * 8);
            o0 = __builtin_amdgcn_mfma_f32_32x32x16_bf16(pf, vf[s][c], o0, 0, 0, 0);
            o1 = __builtin_amdgcn_mfma_f32_32x32x16_bf16(pf, vf[s][4 + c], o1, 0, 0, 0);
        }
    };

    loadf(0, 0);
    for (int k0 = 0; k0 < Ss; k0 += 128) {
        body(0, 1, k0);
        body(1, 0, k0 + 64);
    }

    // epilogue: reduce l across 32 lanes per row, normalize, write, fused amax
    float lmax = 0.f;
    #pragma unroll
    for (int r = 0; r < 16; r++) {
        float l = lp[r];
        #pragma unroll
        for (int off = 1; off < 32; off <<= 1) l += __shfl_xor(l, off, 32);
        float inv = 1.0f / l;
        int row = q0 + wq * 32 + (r & 3) + 8 * (r >> 2) + 4 * h5;
        size_t ro = ((size_t)(b * Ss + row)) * Dd + h * 64;
        float v0 = o0[r] * inv, v1 = o1[r] * inv;
        Ob[ro + ln31] = v0;
        Ob[ro + 32 + ln31] = v1;
        lmax = fmaxf(lmax, fmaxf(fabsf(v0), fabsf(v1)));
    }
    #pragma unroll
    for (int off = 32; off > 0; off >>= 1) lmax = fmaxf(lmax, __shfl_xor(lmax, off, 64));
    if (lane == 0) wred[wq] = lmax;
    __syncthreads();
    if (t == 0) {
        float m = fmaxf(fmaxf(wred[0], wred[1]), fmaxf(wred[2], wred[3]));
        atomicMax(amax_out, __float_as_uint(m));
    }
}

// ---------------- launch ----------------
extern "C" void kernel_launch(void* const* d_in, const int* in_sizes, int n_in,
                              void* d_out, int out_size, void* d_ws, size_t ws_size,
                              hipStream_t stream) {
    const float* hidden = (const float*)d_in[0];
    const float* mask   = (const float*)d_in[1];
    const float* Wq = (const float*)d_in[2];
    const float* bq = (const float*)d_in[3];
    const float* Wk = (const float*)d_in[4];
    const float* bk = (const float*)d_in[5];
    const float* Wv = (const float*)d_in[6];
    const float* bv = (const float*)d_in[7];
    const float* Wo = (const float*)d_in[8];
    const float* bo = (const float*)d_in[9];
    float* out = (float*)d_out;

    char* ws = (char*)d_ws;
    float* scal = (float*)ws;  // amax slots 0..5
    size_t off = 1024;
    const size_t szH8 = (size_t)Mm * Dd;                           // 4 MB
    const size_t szHb = (size_t)Mm * Dd * sizeof(unsigned short);  // 8.39 MB
    const size_t szHf = (size_t)Mm * Dd * sizeof(float);           // 16.78 MB
    char* hq8   = ws + off; off += szH8;
    char* Wall8 = ws + off; off += 4u << 20;  // Wq|Wk|Wv|Wo, 1MB each
    char* aq8   = ws + off; off += szH8;
    unsigned short* qb16 = (unsigned short*)(ws + off); off += szHb;
    unsigned short* kb16 = (unsigned short*)(ws + off); off += szHb;
    unsigned short* vt16 = (unsigned short*)(ws + off); off += szHb;
    float* ab = (float*)(ws + off); off += szHf;

    hipMemsetAsync(scal, 0, 64, stream);

    amax_all<<<512, 256, 0, stream>>>((const float4*)hidden, (const float4*)Wq,
                                      (const float4*)Wk, (const float4*)Wv, (const float4*)Wo,
                                      (unsigned*)scal);
    quant_all<<<1152, 256, 0, stream>>>(hidden, Wq, Wk, Wv, Wo, scal, hq8, Wall8);

    gemm_qkv<<<dim3(24, 32), 256, 0, stream>>>(hq8, Wall8, bq, bk, bv, scal,
                                               qb16, kb16, vt16);

    attn_mfma<<<dim3(Ss / 128, Hh, Bb), 256, 0, stream>>>(qb16, kb16, vt16,
                                                          mask, ab, (unsigned*)(scal + 5));

    quant_a<<<1024, 256, 0, stream>>>(ab, aq8, scal + 5, Mm * Dd / 4);

    gemm_o<<<dim3(16, 32), 256, 0, stream>>>(aq8, Wall8 + (3u << 20), bo,
                                             scal + 5, scal + 4, out);
}

// Round 9
// 230.646 us; speedup vs baseline: 1.3590x; 1.3590x over previous
//
#include <hip/hip_runtime.h>
#include <cstddef>
#include <cstdint>

// Problem constants (B=2, S=2048, D=1024, H=16, hd=64)
constexpr int Bb = 2, Ss = 2048, Dd = 1024, Hh = 16, HD = 64;
constexpr int Mm = Bb * Ss;  // 4096 rows

typedef int v4i __attribute__((ext_vector_type(4)));
typedef __bf16 bf16x8 __attribute__((ext_vector_type(8)));
typedef __bf16 bf16x2 __attribute__((ext_vector_type(2)));
typedef float f32x16 __attribute__((ext_vector_type(16)));

// ln2 folding: q *= 0.125 * 1/ln2 so p = exp2(score) is one v_exp_f32
#define QPOSTMUL 0.18033688f
#define MASKBIAS -14426.950408f   /* -10000 / ln2 */

__device__ __forceinline__ float qscale(float amax) {
    return fmaxf(amax / 127.0f, 1e-8f);
}

// round-to-nearest-even f32 -> bf16 bits
__device__ __forceinline__ unsigned short bf16rtn(float x) {
    __bf16 b = (__bf16)x;
    return __builtin_bit_cast(unsigned short, b);
}

// pack two f32 -> bf16x2 in one u32 (RTN)
__device__ __forceinline__ unsigned pack_bf16x2(float a, float b) {
    unsigned ua = __float_as_uint(a), ub = __float_as_uint(b);
    unsigned ha = (ua + 0x7fffu + ((ua >> 16) & 1u)) >> 16;
    unsigned hb = (ub + 0x7fffu + ((ub >> 16) & 1u)) & 0xffff0000u;
    return ha | hb;
}

// ---------------- fused amax: hidden (slot0) + 4 weights (slots 1-4) ----------------
__global__ void amax_all(const float4* __restrict__ hidden,
                         const float4* __restrict__ w0, const float4* __restrict__ w1,
                         const float4* __restrict__ w2, const float4* __restrict__ w3,
                         unsigned* __restrict__ slots) {
    const float4* src; int n4, slot, bx, nb;
    if (blockIdx.x < 448) { src = hidden; n4 = Mm * Dd / 4; slot = 0; bx = blockIdx.x; nb = 448; }
    else {
        int w = (blockIdx.x - 448) >> 4; bx = (blockIdx.x - 448) & 15; nb = 16;
        src = w == 0 ? w0 : w == 1 ? w1 : w == 2 ? w2 : w3;
        n4 = Dd * Dd / 4; slot = 1 + w;
    }
    float m = 0.f;
    for (int i = bx * blockDim.x + threadIdx.x; i < n4; i += nb * blockDim.x) {
        float4 v = src[i];
        m = fmaxf(m, fmaxf(fmaxf(fabsf(v.x), fabsf(v.y)), fmaxf(fabsf(v.z), fabsf(v.w))));
    }
    #pragma unroll
    for (int off = 32; off > 0; off >>= 1) m = fmaxf(m, __shfl_down(m, off, 64));
    __shared__ float sm[4];
    int lane = threadIdx.x & 63, wid = threadIdx.x >> 6;
    if (lane == 0) sm[wid] = m;
    __syncthreads();
    if (threadIdx.x == 0) {
        float mm = fmaxf(fmaxf(sm[0], sm[1]), fmaxf(sm[2], sm[3]));
        atomicMax(slots + slot, __float_as_uint(mm));  // f32 bits compare as uint for >=0
    }
}

// ---------------- fused quant: hidden -> hq8, 4 weights -> Wall8 (1MB apart) ------------
__global__ void quant_all(const float* __restrict__ hidden,
                          const float* __restrict__ w0, const float* __restrict__ w1,
                          const float* __restrict__ w2, const float* __restrict__ w3,
                          const float* __restrict__ amax,
                          char* __restrict__ hq8, char* __restrict__ Wall8) {
    const float* x; char* y; int n4, slot, bx, nb;
    if (blockIdx.x < 1024) { x = hidden; y = hq8; n4 = Mm * Dd / 4; slot = 0; bx = blockIdx.x; nb = 1024; }
    else {
        int w = (blockIdx.x - 1024) >> 5; bx = (blockIdx.x - 1024) & 31; nb = 32;
        x = w == 0 ? w0 : w == 1 ? w1 : w == 2 ? w2 : w3;
        y = Wall8 + ((size_t)w << 20);
        n4 = Dd * Dd / 4; slot = 1 + w;
    }
    float s = qscale(amax[slot]);
    const float4* x4 = (const float4*)x;
    char4* y4 = (char4*)y;
    for (int i = bx * blockDim.x + threadIdx.x; i < n4; i += nb * blockDim.x) {
        float4 v = x4[i];
        char4 q;
        q.x = (char)(int)rintf(v.x / s);
        q.y = (char)(int)rintf(v.y / s);
        q.z = (char)(int)rintf(v.z / s);
        q.w = (char)(int)rintf(v.w / s);
        y4[i] = q;
    }
}

// quant attn output (scale inline from amax slot)
__global__ void quant_a(const float* __restrict__ x, char* __restrict__ y,
                        const float* __restrict__ amax, int n4) {
    float s = qscale(amax[0]);
    int stride = gridDim.x * blockDim.x;
    const float4* x4 = (const float4*)x;
    char4* y4 = (char4*)y;
    for (int i = blockIdx.x * blockDim.x + threadIdx.x; i < n4; i += stride) {
        float4 v = x4[i];
        char4 q;
        q.x = (char)(int)rintf(v.x / s);
        q.y = (char)(int)rintf(v.y / s);
        q.z = (char)(int)rintf(v.z / s);
        q.w = (char)(int)rintf(v.w / s);
        y4[i] = q;
    }
}

// ---------------- int8 MFMA GEMM core: 128x128 tile, BK=64, 4 waves of 64x64 ------------
#define GLOAD_LDS16(g, l) __builtin_amdgcn_global_load_lds( \
    (const __attribute__((address_space(1))) unsigned int*)(g), \
    (__attribute__((address_space(3))) unsigned int*)(l), 16, 0, 0)

__device__ __forceinline__ void gemm128_core(const char* __restrict__ A, const char* __restrict__ Bw,
                                             int bm, int bn, int K, int t,
                                             char* At, char* Bt, v4i acc[4][4]) {
    const int lane = t & 63, w = t >> 6;
    const int wm = (w >> 1) * 64, wn = (w & 1) * 64;
    const int lr = lane & 15, kq = lane >> 4;
    const int rs = w * 16 + (lane >> 2);  // wave-contiguous staged row
    const int cc = lane & 3;

    for (int k0 = 0; k0 < K; k0 += 64) {
        __syncthreads();
        #pragma unroll
        for (int h = 0; h < 2; h++) {
            int r = rs + h * 64;
            int cs = cc ^ ((r >> 1) & 3);  // source-side XOR swizzle
            GLOAD_LDS16(A  + (size_t)(bm + r) * K + k0 + cs * 16, At + r * 64 + cc * 16);
            GLOAD_LDS16(Bw + (size_t)(bn + r) * K + k0 + cs * 16, Bt + r * 64 + cc * 16);
        }
        __syncthreads();

        v4i af[4], bf[4];
        #pragma unroll
        for (int mt = 0; mt < 4; mt++) {
            int row = wm + mt * 16 + lr;
            af[mt] = *(const v4i*)(At + row * 64 + ((kq ^ ((row >> 1) & 3)) << 4));
        }
        #pragma unroll
        for (int nt = 0; nt < 4; nt++) {
            int row = wn + nt * 16 + lr;
            bf[nt] = *(const v4i*)(Bt + row * 64 + ((kq ^ ((row >> 1) & 3)) << 4));
        }
        #pragma unroll
        for (int mt = 0; mt < 4; mt++)
            #pragma unroll
            for (int nt = 0; nt < 4; nt++)
                acc[mt][nt] = __builtin_amdgcn_mfma_i32_16x16x64_i8(af[mt], bf[nt], acc[mt][nt], 0, 0, 0);
    }
}

// Fused Q/K/V projection with LDS-transpose epilogue (coalesced 16B stores, no write
// amplification). Q: bf16 (pre-scaled by 0.125/ln2); K: bf16; V: bf16 transposed [B,H,64,S].
__global__ __launch_bounds__(256) void gemm_qkv(const char* __restrict__ A,
                                                const char* __restrict__ Wall8,
                                                const float* __restrict__ bq,
                                                const float* __restrict__ bk,
                                                const float* __restrict__ bv,
                                                const float* __restrict__ amax,
                                                unsigned short* __restrict__ qb16,
                                                unsigned short* __restrict__ kb16,
                                                unsigned short* __restrict__ vt16) {
    __shared__ alignas(16) char pool[34816];  // k-loop: At|Bt (16KB); epilogue: 128x136 ushort
    char* At = pool;
    char* Bt = pool + 8192;
    unsigned short (*Tt)[136] = (unsigned short(*)[136])pool;

    const int t = threadIdx.x, lane = t & 63, w = t >> 6;
    const int mat = blockIdx.x >> 3;
    const int bn = (blockIdx.x & 7) * 128, bm = blockIdx.y * 128;
    const int wm = (w >> 1) * 64, wn = (w & 1) * 64;
    const int lr = lane & 15, kq = lane >> 4;

    const v4i vzero = {0, 0, 0, 0};
    v4i acc[4][4];
    #pragma unroll
    for (int mt = 0; mt < 4; mt++)
        #pragma unroll
        for (int nt = 0; nt < 4; nt++) acc[mt][nt] = vzero;

    const char* Bw = Wall8 + ((size_t)mat << 20);
    gemm128_core(A, Bw, bm, bn, Dd, t, At, Bt, acc);

    const float* bias = mat == 0 ? bq : mat == 1 ? bk : bv;
    float sc = qscale(amax[0]) * qscale(amax[1 + mat]);
    float pm = (mat == 0) ? QPOSTMUL : 1.0f;

    __syncthreads();  // all waves done reading At/Bt before Tt overwrites the pool

    // ---- phase A: acc -> bf16 -> LDS tile ----
    if (mat != 2) {
        // Tt[m][n] (row-major target)
        #pragma unroll
        for (int nt = 0; nt < 4; nt++) {
            int n_l = wn + nt * 16 + lr;
            float bv_ = bias[bn + n_l];
            #pragma unroll
            for (int mt = 0; mt < 4; mt++) {
                int m_l = wm + mt * 16 + kq * 4;
                #pragma unroll
                for (int rg = 0; rg < 4; rg++)
                    Tt[m_l + rg][n_l] = bf16rtn(((float)acc[mt][nt][rg] * sc + bv_) * pm);
            }
        }
    } else {
        // Tt[n][m] (V^T target): lane's 4 consecutive m -> one 8B write
        #pragma unroll
        for (int nt = 0; nt < 4; nt++) {
            int n_l = wn + nt * 16 + lr;
            float bv_ = bias[bn + n_l];
            #pragma unroll
            for (int mt = 0; mt < 4; mt++) {
                int m_l = wm + mt * 16 + kq * 4;
                ushort4 hv;
                hv.x = bf16rtn((float)acc[mt][nt][0] * sc + bv_);
                hv.y = bf16rtn((float)acc[mt][nt][1] * sc + bv_);
                hv.z = bf16rtn((float)acc[mt][nt][2] * sc + bv_);
                hv.w = bf16rtn((float)acc[mt][nt][3] * sc + bv_);
                *(ushort4*)&Tt[n_l][m_l] = hv;
            }
        }
    }
    __syncthreads();

    // ---- phase B: coalesced 16B stores of contiguous 256B rows ----
    {
        int row = t >> 1, half = t & 1;
        unsigned short* dst;
        if (mat != 2) {
            dst = (mat == 0 ? qb16 : kb16) + (size_t)(bm + row) * Dd + bn + half * 64;
        } else {
            int n = bn + row;
            int e = n & 63, hc = n >> 6;
            int b_ = bm >> 11, s_ = (bm & 2047) + half * 64;
            dst = vt16 + (((size_t)(b_ * Hh + hc) * 64 + e) * Ss) + s_;
        }
        const unsigned short* srcl = &Tt[row][half * 64];
        #pragma unroll
        for (int c = 0; c < 8; c++)
            *(int4*)(dst + c * 8) = *(const int4*)(srcl + c * 8);
    }
}

// O-projection: 128m x 64n tile -> 512 blocks (2/CU) for latency overlap. f32 output.
__global__ __launch_bounds__(256) void gemm_o(const char* __restrict__ A,
                                              const char* __restrict__ Bw,
                                              const float* __restrict__ bias,
                                              const float* __restrict__ amaxA,
                                              const float* __restrict__ amaxB,
                                              float* __restrict__ C) {
    __shared__ alignas(16) char At[128 * 64];
    __shared__ alignas(16) char Bt[64 * 64];
    const int t = threadIdx.x, lane = t & 63, w = t >> 6;
    const int bn = blockIdx.x * 64, bm = blockIdx.y * 128;
    const int wm = (w >> 1) * 64, wn = (w & 1) * 32;
    const int lr = lane & 15, kq = lane >> 4;
    const int rs = t >> 2, cc = t & 3;
    const int cs = cc ^ ((rs >> 1) & 3);
    const int rs2 = rs + 64, cs2 = cc ^ ((rs2 >> 1) & 3);

    const v4i vzero = {0, 0, 0, 0};
    v4i acc[4][2];
    #pragma unroll
    for (int mt = 0; mt < 4; mt++) { acc[mt][0] = vzero; acc[mt][1] = vzero; }

    for (int k0 = 0; k0 < Dd; k0 += 64) {
        __syncthreads();
        GLOAD_LDS16(A  + (size_t)(bm + rs)  * Dd + k0 + cs  * 16, At + rs  * 64 + cc * 16);
        GLOAD_LDS16(A  + (size_t)(bm + rs2) * Dd + k0 + cs2 * 16, At + rs2 * 64 + cc * 16);
        GLOAD_LDS16(Bw + (size_t)(bn + rs)  * Dd + k0 + cs  * 16, Bt + rs  * 64 + cc * 16);
        __syncthreads();

        v4i af[4], bf[2];
        #pragma unroll
        for (int mt = 0; mt < 4; mt++) {
            int row = wm + mt * 16 + lr;
            af[mt] = *(const v4i*)(At + row * 64 + ((kq ^ ((row >> 1) & 3)) << 4));
        }
        #pragma unroll
        for (int nt = 0; nt < 2; nt++) {
            int row = wn + nt * 16 + lr;
            bf[nt] = *(const v4i*)(Bt + row * 64 + ((kq ^ ((row >> 1) & 3)) << 4));
        }
        #pragma unroll
        for (int mt = 0; mt < 4; mt++)
            #pragma unroll
            for (int nt = 0; nt < 2; nt++)
                acc[mt][nt] = __builtin_amdgcn_mfma_i32_16x16x64_i8(af[mt], bf[nt], acc[mt][nt], 0, 0, 0);
    }

    float sc = qscale(amaxA[0]) * qscale(amaxB[0]);
    #pragma unroll
    for (int nt = 0; nt < 2; nt++) {
        int n = bn + wn + nt * 16 + lr;
        float bv_ = bias[n];
        #pragma unroll
        for (int mt = 0; mt < 4; mt++)
            #pragma unroll
            for (int rg = 0; rg < 4; rg++) {
                int m = bm + wm + mt * 16 + kq * 4 + rg;
                C[(size_t)m * Dd + n] = (float)acc[mt][nt][rg] * sc + bv_;
            }
    }
}

// ---------------- MFMA flash attention (r6 structure — best measured: 76.2 µs) ----------
// Single-bf16 QK, no-max exp2 softmax. K rows interleave-permuted so tile0/tile1 =
// even/odd cols -> (p0,p1) pack to one ds_write_b32. Next K/V tile prefetched into regs
// during compute; LDS staging keeps global loads coalesced (r8 lesson).
__global__ __launch_bounds__(256) void attn_mfma(
    const unsigned short* __restrict__ qb16, const unsigned short* __restrict__ kb16,
    const unsigned short* __restrict__ vt16,
    const float* __restrict__ mask, float* __restrict__ Ob, unsigned* __restrict__ amax_out) {
    __shared__ alignas(16) unsigned short KsHi[64][72], VsHi[64][72];
    __shared__ alignas(16) unsigned PwU[4][32][36];  // packed (p_even, p_odd)
    __shared__ float mbias[64];
    __shared__ float wred[4];

    const int t = threadIdx.x, lane = t & 63, wq = t >> 6;
    const int ln31 = lane & 31, h5 = lane >> 5;
    const int b = blockIdx.z, h = blockIdx.y, q0 = blockIdx.x * 128;

    // Q fragments (A operand): row = q0 + wq*32 + ln31, k = c*16 + h5*8 + j
    bf16x8 qf[4];
    {
        int qrow = q0 + wq * 32 + ln31;
        const unsigned short* qb_ = qb16 + ((size_t)(b * Ss + qrow)) * Dd + h * 64 + h5 * 8;
        #pragma unroll
        for (int c = 0; c < 4; c++) qf[c] = *(const bf16x8*)(qb_ + c * 16);
    }

    const int srow = t >> 2, cp = (t & 3) * 2;
    const int rho = (srow >> 1) + (srow & 1) * 32;  // interleave permute for K
    int4 pk0, pk1, pv0, pv1; float pmask = 1.f;
    auto prefetch = [&](int k0) {
        const unsigned short* gk = kb16 + ((size_t)(b * Ss + k0 + srow)) * Dd + h * 64 + cp * 8;
        const unsigned short* gv = vt16 + (((size_t)(b * Hh + h) * 64 + srow)) * Ss + k0 + cp * 8;
        pk0 = *(const int4*)gk; pk1 = *(const int4*)(gk + 8);
        pv0 = *(const int4*)gv; pv1 = *(const int4*)(gv + 8);
        if (t < 64) pmask = mask[b * Ss + k0 + t];
    };

    f32x16 o0 = 0.f, o1 = 0.f;
    float lp[16];
    #pragma unroll
    for (int r = 0; r < 16; r++) lp[r] = 0.f;

    prefetch(0);
    for (int k0 = 0; k0 < Ss; k0 += 64) {
        __syncthreads();
        *(int4*)&KsHi[rho][cp * 8]      = pk0;
        *(int4*)&KsHi[rho][cp * 8 + 8]  = pk1;
        *(int4*)&VsHi[srow][cp * 8]     = pv0;
        *(int4*)&VsHi[srow][cp * 8 + 8] = pv1;
        if (t < 64) mbias[t] = (1.0f - pmask) * MASKBIAS;
        __syncthreads();
        if (k0 + 64 < Ss) prefetch(k0 + 64);  // in flight during MFMA phase

        // QK^T: tile0 = even orig cols (2*ln31), tile1 = odd (2*ln31+1)
        f32x16 sc0 = 0.f, sc1 = 0.f;
        #pragma unroll
        for (int c = 0; c < 4; c++) {
            bf16x8 kh0 = *(const bf16x8*)&KsHi[ln31][c * 16 + h5 * 8];
            bf16x8 kh1 = *(const bf16x8*)&KsHi[32 + ln31][c * 16 + h5 * 8];
            sc0 = __builtin_amdgcn_mfma_f32_32x32x16_bf16(qf[c], kh0, sc0, 0, 0, 0);
            sc1 = __builtin_amdgcn_mfma_f32_32x32x16_bf16(qf[c], kh1, sc1, 0, 0, 0);
        }

        // p = exp2(logit + mbias); accumulate l per-lane; pack pair -> one ds_write_b32
        float mb0 = mbias[2 * ln31], mb1 = mbias[2 * ln31 + 1];
        #pragma unroll
        for (int r = 0; r < 16; r++) {
            float p0 = __builtin_amdgcn_exp2f(sc0[r] + mb0);
            float p1 = __builtin_amdgcn_exp2f(sc1[r] + mb1);
            lp[r] += p0 + p1;
            int row = (r & 3) + 8 * (r >> 2) + 4 * h5;
            PwU[wq][row][ln31] = pack_bf16x2(p0, p1);
        }

        // PV: O += P * V (per-wave Pw; wave-internal DS ordering, no barrier needed)
        #pragma unroll
        for (int c = 0; c < 4; c++) {
            bf16x8 pf = *(const bf16x8*)((const unsigned short*)&PwU[wq][ln31][0] + c * 16 + h5 * 8);
            bf16x8 vh0 = *(const bf16x8*)&VsHi[ln31][c * 16 + h5 * 8];
            bf16x8 vh1 = *(const bf16x8*)&VsHi[32 + ln31][c * 16 + h5 * 8];
            o0 = __builtin_amdgcn_mfma_f32_32x32x16_bf16(pf, vh0, o0, 0, 0, 0);
            o1 = __builtin_amdgcn_mfma_f32_32x32x16_bf16(pf, vh1, o1, 0, 0, 0);
        }
    }

    // epilogue: reduce l across 32 lanes per row, normalize, write, fused amax
    float lmax = 0.f;
    #pragma unroll
    for (int r = 0; r < 16; r++) {
        float l = lp[r];
        #pragma unroll
        for (int off = 1; off < 32; off <<= 1) l += __shfl_xor(l, off, 32);
        float inv = 1.0f / l;
        int row = q0 + wq * 32 + (r & 3) + 8 * (r >> 2) + 4 * h5;
        size_t ro = ((size_t)(b * Ss + row)) * Dd + h * 64;
        float v0 = o0[r] * inv, v1 = o1[r] * inv;
        Ob[ro + ln31] = v0;
        Ob[ro + 32 + ln31] = v1;
        lmax = fmaxf(lmax, fmaxf(fabsf(v0), fabsf(v1)));
    }
    #pragma unroll
    for (int off = 32; off > 0; off >>= 1) lmax = fmaxf(lmax, __shfl_xor(lmax, off, 64));
    if (lane == 0) wred[wq] = lmax;
    __syncthreads();
    if (t == 0) {
        float m = fmaxf(fmaxf(wred[0], wred[1]), fmaxf(wred[2], wred[3]));
        atomicMax(amax_out, __float_as_uint(m));
    }
}

// ---------------- launch ----------------
extern "C" void kernel_launch(void* const* d_in, const int* in_sizes, int n_in,
                              void* d_out, int out_size, void* d_ws, size_t ws_size,
                              hipStream_t stream) {
    const float* hidden = (const float*)d_in[0];
    const float* mask   = (const float*)d_in[1];
    const float* Wq = (const float*)d_in[2];
    const float* bq = (const float*)d_in[3];
    const float* Wk = (const float*)d_in[4];
    const float* bk = (const float*)d_in[5];
    const float* Wv = (const float*)d_in[6];
    const float* bv = (const float*)d_in[7];
    const float* Wo = (const float*)d_in[8];
    const float* bo = (const float*)d_in[9];
    float* out = (float*)d_out;

    char* ws = (char*)d_ws;
    float* scal = (float*)ws;  // amax slots 0..5
    size_t off = 1024;
    const size_t szH8 = (size_t)Mm * Dd;                           // 4 MB
    const size_t szHb = (size_t)Mm * Dd * sizeof(unsigned short);  // 8.39 MB
    const size_t szHf = (size_t)Mm * Dd * sizeof(float);           // 16.78 MB
    char* hq8   = ws + off; off += szH8;
    char* Wall8 = ws + off; off += 4u << 20;  // Wq|Wk|Wv|Wo, 1MB each
    char* aq8   = ws + off; off += szH8;
    unsigned short* qb16 = (unsigned short*)(ws + off); off += szHb;
    unsigned short* kb16 = (unsigned short*)(ws + off); off += szHb;
    unsigned short* vt16 = (unsigned short*)(ws + off); off += szHb;
    float* ab = (float*)(ws + off); off += szHf;

    hipMemsetAsync(scal, 0, 64, stream);

    amax_all<<<512, 256, 0, stream>>>((const float4*)hidden, (const float4*)Wq,
                                      (const float4*)Wk, (const float4*)Wv, (const float4*)Wo,
                                      (unsigned*)scal);
    quant_all<<<1152, 256, 0, stream>>>(hidden, Wq, Wk, Wv, Wo, scal, hq8, Wall8);

    gemm_qkv<<<dim3(24, 32), 256, 0, stream>>>(hq8, Wall8, bq, bk, bv, scal,
                                               qb16, kb16, vt16);

    attn_mfma<<<dim3(Ss / 128, Hh, Bb), 256, 0, stream>>>(qb16, kb16, vt16,
                                                          mask, ab, (unsigned*)(scal + 5));

    quant_a<<<1024, 256, 0, stream>>>(ab, aq8, scal + 5, Mm * Dd / 4);

    gemm_o<<<dim3(16, 32), 256, 0, stream>>>(aq8, Wall8 + (3u << 20), bo,
                                             scal + 5, scal + 4, out);
}